// Round 8
// baseline (150.918 us; speedup 1.0000x reference)
//
#include <hip/hip_runtime.h>

#define IDX_BASE 16777216UL   // 4096*64*64
#define LOSS_IDX 17039360UL   // IDX_BASE + 4096*64
#define EPS2 0.02f            // rescue window on (M1 - M2); score err bound ~1e-3
#define NCHUNK 4
#define CROWS 64

typedef float4 f4;
typedef _Float16 half8 __attribute__((ext_vector_type(8)));
typedef float f32x4 __attribute__((ext_vector_type(4)));

__device__ __forceinline__ void gload_lds16(const float* g, float* s) {
    __builtin_amdgcn_global_load_lds(
        (const __attribute__((address_space(1))) unsigned int*)g,
        (__attribute__((address_space(3))) unsigned int*)s, 16, 0, 0);
}

// ---- c2[m][k] = ||codebook[m][k]||^2 (fp32, same table rescue uses) ----
__global__ __launch_bounds__(256) void pq_c2(const float* __restrict__ cb,
                                             float* __restrict__ c2) {
    int m = blockIdx.x, k = threadIdx.x;
    const f4* row = reinterpret_cast<const f4*>(cb + ((size_t)m * 256 + k) * 64);
    float s0 = 0.f, s1 = 0.f;
    #pragma unroll
    for (int i = 0; i < 16; i += 2) {
        f4 a = row[i], b = row[i + 1];
        s0 = fmaf(a.x,a.x,s0); s0 = fmaf(a.y,a.y,s0); s0 = fmaf(a.z,a.z,s0); s0 = fmaf(a.w,a.w,s0);
        s1 = fmaf(b.x,b.x,s1); s1 = fmaf(b.y,b.y,s1); s1 = fmaf(b.z,b.z,s1); s1 = fmaf(b.w,b.w,s1);
    }
    c2[m * 256 + k] = s0 + s1;
}

// Persistent block = one m x 4 chunks of 64 rows. 4 waves; wave w owns codes
// w*64..+63 as f16 hi/lo A-fragments in registers (amortized over 4 chunks).
// z double-buffered in LDS: stage(c+1) issued before compute(c).
__global__ __launch_bounds__(256, 4) void pq_main(
    const float* __restrict__ z, const float* __restrict__ cb,
    const float* __restrict__ c2ws,
    float* __restrict__ out, float* __restrict__ partial)
{
    __shared__ f4    sZ4[2][CROWS * 16];   // 2 x 16 KB; [r*16+c4] = z[r][(c4^(r&7))*4..]
    __shared__ float sM1[4 * CROWS];
    __shared__ float sM2[4 * CROWS];
    __shared__ int   sK [4 * CROWS];
    __shared__ int   sBest[CROWS];
    __shared__ float sW[4];

    const int tid = threadIdx.x, bx = blockIdx.x;
    const int m = bx >> 4, g = bx & 15;         // block handles chunks g*4..g*4+3
    const int w = tid >> 6, lane = tid & 63;
    const int lh = lane >> 4, l15 = lane & 15;
    const int cbase = g * NCHUNK;

    const float* __restrict__ cbm = cb + (size_t)m * (256 * 64);
    const f4* cb4m = reinterpret_cast<const f4*>(cbm);

    // ---- stage one 64-row chunk c into buffer bb (pre-swizzled src, linear LDS) ----
    auto stage = [&](int c, int bb) {
        #pragma unroll
        for (int i = 0; i < 4; ++i) {
            int unit = i * 256 + w * 64 + lane;
            int row = unit >> 4, c4 = unit & 15;
            int c4p = c4 ^ (row & 7);
            const float* src = z + ((size_t)(c * 64 + row) * 64 + m) * 64 + c4p * 4;
            gload_lds16(src, (float*)&sZ4[bb][i * 256 + w * 64]);
        }
    };
    stage(cbase, 0);   // prologue: chunk 0 -> buf 0 (DMA rides under A-frag build)

    // ---- A-fragments: wave's 64 codes, f16 hi/lo, k-map (lh*8+e per s) ----
    half8 ah[4][2], al[4][2];
    #pragma unroll
    for (int t = 0; t < 4; ++t) {
        int code = (w * 4 + t) * 16 + l15;
        const float* crow = cbm + code * 64 + lh * 8;
        #pragma unroll
        for (int s = 0; s < 2; ++s) {
            f4 a = *reinterpret_cast<const f4*>(crow + s * 32);
            f4 b = *reinterpret_cast<const f4*>(crow + s * 32 + 4);
            float v[8] = {a.x, a.y, a.z, a.w, b.x, b.y, b.z, b.w};
            #pragma unroll
            for (int e = 0; e < 8; ++e) {
                _Float16 h = (_Float16)v[e];
                ah[t][s][e] = h;
                al[t][s][e] = (_Float16)(v[e] - (float)h);
            }
        }
    }
    // ---- c2 init per lane: k = w*64 + t*16 + lh*4 + r ----
    f32x4 c2i[4];
    #pragma unroll
    for (int t = 0; t < 4; ++t)
        #pragma unroll
        for (int r = 0; r < 4; ++r)
            c2i[t][r] = -0.5f * c2ws[m * 256 + w * 64 + t * 16 + lh * 4 + r];

    float lacc = 0.f;

    #pragma unroll 1
    for (int cc = 0; cc < NCHUNK; ++cc) {
        const int cur = cc & 1, nxt = cur ^ 1;
        const int c = cbase + cc;
        __syncthreads();                    // drains DMA for buf[cur]; frees buf[nxt]
        if (cc + 1 < NCHUNK) stage(c + 1, nxt);   // DMA overlaps this chunk's compute
        const f4* zt = sZ4[cur];

        // ---- 4 row-tiles x {on-the-fly B-frag convert + 4x6 MFMA + top-2} ----
        #pragma unroll 1
        for (int rt = 0; rt < 4; ++rt) {
            const int row = rt * 16 + l15;
            const int swz = row & 7;
            const f4* zr = &zt[row * 16];
            const int c0 = lh << 1;
            f4 a0 = zr[(c0)     ^ swz];
            f4 a1 = zr[(c0 + 1) ^ swz];
            f4 a2 = zr[(c0 + 8) ^ swz];
            f4 a3 = zr[(c0 + 9) ^ swz];
            half8 bh0, bl0, bh1, bl1;
            {
                float v0[8] = {a0.x, a0.y, a0.z, a0.w, a1.x, a1.y, a1.z, a1.w};
                float v1[8] = {a2.x, a2.y, a2.z, a2.w, a3.x, a3.y, a3.z, a3.w};
                #pragma unroll
                for (int e = 0; e < 8; ++e) {
                    _Float16 h0 = (_Float16)v0[e];
                    bh0[e] = h0; bl0[e] = (_Float16)(v0[e] - (float)h0);
                    _Float16 h1 = (_Float16)v1[e];
                    bh1[e] = h1; bl1[e] = (_Float16)(v1[e] - (float)h1);
                }
            }
            float m1 = -1e30f, m2 = -1e30f; int k16 = 0;
            #pragma unroll
            for (int t = 0; t < 4; ++t) {
                f32x4 acc = c2i[t];
                acc = __builtin_amdgcn_mfma_f32_16x16x32_f16(ah[t][0], bh0, acc, 0, 0, 0);
                acc = __builtin_amdgcn_mfma_f32_16x16x32_f16(ah[t][1], bh1, acc, 0, 0, 0);
                acc = __builtin_amdgcn_mfma_f32_16x16x32_f16(ah[t][0], bl0, acc, 0, 0, 0);
                acc = __builtin_amdgcn_mfma_f32_16x16x32_f16(ah[t][1], bl1, acc, 0, 0, 0);
                acc = __builtin_amdgcn_mfma_f32_16x16x32_f16(al[t][0], bh0, acc, 0, 0, 0);
                acc = __builtin_amdgcn_mfma_f32_16x16x32_f16(al[t][1], bh1, acc, 0, 0, 0);
                #pragma unroll
                for (int r = 0; r < 4; ++r) {
                    float v = acc[r];
                    m2 = fmaxf(m2, fminf(v, m1));      // classic top-2 update
                    bool gt = v > m1;
                    m1  = gt ? v : m1;
                    k16 = gt ? (t * 16 + r) : k16;
                }
            }
            int kw = k16 + lh * 4;
            #pragma unroll
            for (int off = 16; off <= 32; off <<= 1) {   // merge 4 lane-groups per row
                float om1 = __shfl_xor(m1, off, 64);
                float om2 = __shfl_xor(m2, off, 64);
                int   okw = __shfl_xor(kw, off, 64);
                m2 = fmaxf(fmaxf(m2, om2), fminf(m1, om1));
                bool better = (om1 > m1) || (om1 == m1 && okw < kw);
                m1 = better ? om1 : m1;
                kw = better ? okw : kw;
            }
            if (lane < 16) {
                int r2 = rt * 16 + lane;
                sM1[w * CROWS + r2] = m1;
                sM2[w * CROWS + r2] = m2;
                sK [w * CROWS + r2] = kw;
            }
        }
        __syncthreads();

        // ---- per-row merge across 4 waves; flag near-ties for exact rescue ----
        if (tid < CROWS) {
            float M1 = -1e30f, M2 = -1e30f; int K1 = 0;
            #pragma unroll
            for (int w2 = 0; w2 < 4; ++w2) {
                float v1 = sM1[w2 * CROWS + tid];
                float v2 = sM2[w2 * CROWS + tid];
                int   kk = w2 * 64 + sK[w2 * CROWS + tid];
                M2 = fmaxf(fmaxf(M2, v2), fminf(M1, v1));
                bool better = v1 > M1;       // w ascending: ties keep smaller k
                M1 = better ? v1 : M1;
                K1 = better ? kk : K1;
            }
            sBest[tid] = (M1 - M2 < EPS2) ? -1 : K1;
        }
        __syncthreads();

        // ---- rescue (rare): exact fp32 rescan (validated R4 arithmetic) ----
        for (int row = w; row < CROWS; row += 4) {
            if (sBest[row] >= 0) continue;            // wave-uniform
            int swz = row & 7;
            float bs = -1e30f; int bk = 0;
            #pragma unroll 1
            for (int j = 0; j < 4; ++j) {
                int k = j * 64 + lane;
                float s = -0.5f * c2ws[m * 256 + k];
                #pragma unroll
                for (int d4 = 0; d4 < 16; ++d4) {
                    f4 cvv = cb4m[k * 16 + d4];
                    f4 zz  = zt[row * 16 + (d4 ^ swz)];
                    s = fmaf(zz.x, cvv.x, s); s = fmaf(zz.y, cvv.y, s);
                    s = fmaf(zz.z, cvv.z, s); s = fmaf(zz.w, cvv.w, s);
                }
                if (s > bs) { bs = s; bk = k; }
            }
            #pragma unroll
            for (int off = 1; off < 64; off <<= 1) {
                float ov = __shfl_xor(bs, off, 64);
                int   ok = __shfl_xor(bk, off, 64);
                if (ov > bs || (ov == bs && ok < bk)) { bs = ov; bk = ok; }
            }
            if (lane == 0) sBest[row] = bk;
        }
        __syncthreads();

        // ---- outputs: quantized (exact codebook copy), index, loss accumulate ----
        {
            int row = tid >> 2, quad = tid & 3;
            int k = sBest[row];
            int b = c * 64 + row;
            int swz = row & 7;
            const f4* q4 = cb4m + (size_t)k * 16 + quad * 4;
            f4*       o4 = reinterpret_cast<f4*>(out + ((size_t)b * 64 + m) * 64) + quad * 4;
            #pragma unroll
            for (int e = 0; e < 4; ++e) {
                f4 qv = q4[e];
                f4 zv = zt[row * 16 + ((quad * 4 + e) ^ swz)];
                o4[e] = qv;
                float d0 = qv.x - zv.x, d1 = qv.y - zv.y;
                float d2 = qv.z - zv.z, d3 = qv.w - zv.w;
                lacc = fmaf(d0, d0, lacc); lacc = fmaf(d1, d1, lacc);
                lacc = fmaf(d2, d2, lacc); lacc = fmaf(d3, d3, lacc);
            }
        }
        if (tid < CROWS)
            out[IDX_BASE + (size_t)(c * 64 + tid) * 64 + m] = (float)sBest[tid];
        // next iteration's top barrier protects buf reuse
    }

    // ---- loss partial: one reduction for all 4 chunks ----
    #pragma unroll
    for (int off = 1; off < 64; off <<= 1) lacc += __shfl_xor(lacc, off, 64);
    if (lane == 0) sW[w] = lacc;
    __syncthreads();
    if (tid == 0) partial[bx] = (sW[0] + sW[1]) + (sW[2] + sW[3]);
}

// ---- deterministic final reduction of 1024 block partials -> q_loss ----
__global__ __launch_bounds__(256) void pq_loss(const float* __restrict__ partial,
                                               float* __restrict__ out)
{
    __shared__ float sW[4];
    float s = (partial[threadIdx.x]       + partial[threadIdx.x + 256])
            + (partial[threadIdx.x + 512] + partial[threadIdx.x + 768]);
    #pragma unroll
    for (int off = 1; off < 64; off <<= 1) s += __shfl_xor(s, off, 64);
    if ((threadIdx.x & 63) == 0) sW[threadIdx.x >> 6] = s;
    __syncthreads();
    if (threadIdx.x == 0)
        out[LOSS_IDX] = ((sW[0] + sW[1]) + (sW[2] + sW[3])) * (1.25f / 16777216.0f);
}

extern "C" void kernel_launch(void* const* d_in, const int* in_sizes, int n_in,
                              void* d_out, int out_size, void* d_ws, size_t ws_size,
                              hipStream_t stream) {
    const float* zp  = (const float*)d_in[0];
    const float* cbp = (const float*)d_in[1];
    float* outp = (float*)d_out;
    float* c2ws = (float*)d_ws;                  // 64*256 floats = 64 KB
    float* part = (float*)d_ws + 64 * 256;       // 1024 floats

    pq_c2  <<<dim3(64),   dim3(256), 0, stream>>>(cbp, c2ws);
    pq_main<<<dim3(1024), dim3(256), 0, stream>>>(zp, cbp, c2ws, outp, part);
    pq_loss<<<dim3(1),    dim3(256), 0, stream>>>(part, outp);
}

// Round 9
// 98.345 us; speedup vs baseline: 1.5346x; 1.5346x over previous
//
#include <hip/hip_runtime.h>

#define IDX_BASE 16777216UL   // 4096*64*64
#define LOSS_IDX 17039360UL   // IDX_BASE + 4096*64
#define EPS2 0.02f            // rescue window on (M1 - M2); score err bound ~1e-3
#define CROWS 64

typedef float4 f4;
typedef _Float16 half8 __attribute__((ext_vector_type(8)));
typedef float f32x4 __attribute__((ext_vector_type(4)));

__device__ __forceinline__ void gload_lds16(const float* g, float* s) {
    __builtin_amdgcn_global_load_lds(
        (const __attribute__((address_space(1))) unsigned int*)g,
        (__attribute__((address_space(3))) unsigned int*)s, 16, 0, 0);
}

// ---- c2[m][k] = ||codebook[m][k]||^2 (fp32, same table rescue uses) ----
__global__ __launch_bounds__(256) void pq_c2(const float* __restrict__ cb,
                                             float* __restrict__ c2) {
    int m = blockIdx.x, k = threadIdx.x;
    const f4* row = reinterpret_cast<const f4*>(cb + ((size_t)m * 256 + k) * 64);
    float s0 = 0.f, s1 = 0.f;
    #pragma unroll
    for (int i = 0; i < 16; i += 2) {
        f4 a = row[i], b = row[i + 1];
        s0 = fmaf(a.x,a.x,s0); s0 = fmaf(a.y,a.y,s0); s0 = fmaf(a.z,a.z,s0); s0 = fmaf(a.w,a.w,s0);
        s1 = fmaf(b.x,b.x,s1); s1 = fmaf(b.y,b.y,s1); s1 = fmaf(b.z,b.z,s1); s1 = fmaf(b.w,b.w,s1);
    }
    c2[m * 256 + k] = s0 + s1;
}

// Block = one m x 64 rows, 256 threads (4 waves). Wave w owns codes w*64..+63 as
// f16 hi/lo A-fragments in registers; z staged fp32 in LDS (swizzled); B-fragments
// converted on the fly per row-tile. LDS ~19.3 KB -> 8 blocks/CU (TLP doubled vs R7).
__global__ __launch_bounds__(256, 4) void pq_main(
    const float* __restrict__ z, const float* __restrict__ cb,
    const float* __restrict__ c2ws,
    float* __restrict__ out, float* __restrict__ partial)
{
    __shared__ f4    sZ4[CROWS * 16];   // 16 KB; sZ4[r*16+c4] = z[r][(c4^(r&7))*4..]
    __shared__ float sM1[4 * CROWS];
    __shared__ float sM2[4 * CROWS];
    __shared__ int   sK [4 * CROWS];
    __shared__ int   sBest[CROWS];
    __shared__ float sW[4];

    const int tid = threadIdx.x, bx = blockIdx.x;
    const int m = bx >> 6, chunk = bx & 63;     // 64 consecutive blocks share m
    const int w = tid >> 6, lane = tid & 63;
    const int lh = lane >> 4, l15 = lane & 15;

    const float* __restrict__ cbm = cb + (size_t)m * (256 * 64);
    const f4* cb4m = reinterpret_cast<const f4*>(cbm);

    // ---- stage z fp32 (pre-swizzled source -> linear LDS), fire DMA first ----
    #pragma unroll
    for (int i = 0; i < 4; ++i) {
        int unit = i * 256 + w * 64 + lane;
        int row = unit >> 4, c4 = unit & 15;
        int c4p = c4 ^ (row & 7);
        const float* src = z + ((size_t)(chunk * 64 + row) * 64 + m) * 64 + c4p * 4;
        gload_lds16(src, (float*)&sZ4[i * 256 + w * 64]);
    }

    // ---- A-fragments: wave's 64 codes, f16 hi/lo, k-map (lh*8+e per s) ----
    half8 ah[4][2], al[4][2];
    #pragma unroll
    for (int t = 0; t < 4; ++t) {
        int code = (w * 4 + t) * 16 + l15;
        const float* crow = cbm + code * 64 + lh * 8;
        #pragma unroll
        for (int s = 0; s < 2; ++s) {
            f4 a = *reinterpret_cast<const f4*>(crow + s * 32);
            f4 b = *reinterpret_cast<const f4*>(crow + s * 32 + 4);
            float v[8] = {a.x, a.y, a.z, a.w, b.x, b.y, b.z, b.w};
            #pragma unroll
            for (int e = 0; e < 8; ++e) {
                _Float16 h = (_Float16)v[e];
                ah[t][s][e] = h;
                al[t][s][e] = (_Float16)(v[e] - (float)h);
            }
        }
    }
    // ---- c2 init per lane: k = w*64 + t*16 + lh*4 + r ----
    f32x4 c2i[4];
    #pragma unroll
    for (int t = 0; t < 4; ++t)
        #pragma unroll
        for (int r = 0; r < 4; ++r)
            c2i[t][r] = -0.5f * c2ws[m * 256 + w * 64 + t * 16 + lh * 4 + r];

    __syncthreads();   // z staged

    // ---- main: 4 row-tiles x {on-the-fly B-frag convert + 4x6 MFMA + top-2} ----
    #pragma unroll 1
    for (int rt = 0; rt < 4; ++rt) {
        const int row = rt * 16 + l15;
        const int swz = row & 7;
        const f4* zr = &sZ4[row * 16];
        const int c0 = lh << 1;
        f4 a0 = zr[(c0)     ^ swz];
        f4 a1 = zr[(c0 + 1) ^ swz];
        f4 a2 = zr[(c0 + 8) ^ swz];
        f4 a3 = zr[(c0 + 9) ^ swz];
        half8 bh0, bl0, bh1, bl1;
        {
            float v0[8] = {a0.x, a0.y, a0.z, a0.w, a1.x, a1.y, a1.z, a1.w};
            float v1[8] = {a2.x, a2.y, a2.z, a2.w, a3.x, a3.y, a3.z, a3.w};
            #pragma unroll
            for (int e = 0; e < 8; ++e) {
                _Float16 h0 = (_Float16)v0[e];
                bh0[e] = h0; bl0[e] = (_Float16)(v0[e] - (float)h0);
                _Float16 h1 = (_Float16)v1[e];
                bh1[e] = h1; bl1[e] = (_Float16)(v1[e] - (float)h1);
            }
        }
        float m1 = -1e30f, m2 = -1e30f; int k16 = 0;
        #pragma unroll
        for (int t = 0; t < 4; ++t) {
            f32x4 acc = c2i[t];
            acc = __builtin_amdgcn_mfma_f32_16x16x32_f16(ah[t][0], bh0, acc, 0, 0, 0);
            acc = __builtin_amdgcn_mfma_f32_16x16x32_f16(ah[t][1], bh1, acc, 0, 0, 0);
            acc = __builtin_amdgcn_mfma_f32_16x16x32_f16(ah[t][0], bl0, acc, 0, 0, 0);
            acc = __builtin_amdgcn_mfma_f32_16x16x32_f16(ah[t][1], bl1, acc, 0, 0, 0);
            acc = __builtin_amdgcn_mfma_f32_16x16x32_f16(al[t][0], bh0, acc, 0, 0, 0);
            acc = __builtin_amdgcn_mfma_f32_16x16x32_f16(al[t][1], bh1, acc, 0, 0, 0);
            #pragma unroll
            for (int r = 0; r < 4; ++r) {
                float v = acc[r];
                m2 = fmaxf(m2, fminf(v, m1));      // classic top-2 update
                bool gt = v > m1;
                m1  = gt ? v : m1;
                k16 = gt ? (t * 16 + r) : k16;
            }
        }
        int kw = k16 + lh * 4;                     // k within wave's 64 codes
        #pragma unroll
        for (int off = 16; off <= 32; off <<= 1) { // merge the 4 lane-groups per row
            float om1 = __shfl_xor(m1, off, 64);
            float om2 = __shfl_xor(m2, off, 64);
            int   okw = __shfl_xor(kw, off, 64);
            m2 = fmaxf(fmaxf(m2, om2), fminf(m1, om1));
            bool better = (om1 > m1) || (om1 == m1 && okw < kw);
            m1 = better ? om1 : m1;
            kw = better ? okw : kw;
        }
        if (lane < 16) {
            int r2 = rt * 16 + lane;
            sM1[w * CROWS + r2] = m1;
            sM2[w * CROWS + r2] = m2;
            sK [w * CROWS + r2] = kw;
        }
    }
    __syncthreads();

    // ---- per-row merge across 4 waves; flag near-ties for exact rescue ----
    if (tid < CROWS) {
        float M1 = -1e30f, M2 = -1e30f; int K1 = 0;
        #pragma unroll
        for (int w2 = 0; w2 < 4; ++w2) {
            float v1 = sM1[w2 * CROWS + tid];
            float v2 = sM2[w2 * CROWS + tid];
            int   kk = w2 * 64 + sK[w2 * CROWS + tid];
            M2 = fmaxf(fmaxf(M2, v2), fminf(M1, v1));
            bool better = v1 > M1;      // w ascending: ties keep smaller k
            M1 = better ? v1 : M1;
            K1 = better ? kk : K1;
        }
        sBest[tid] = (M1 - M2 < EPS2) ? -1 : K1;
    }
    __syncthreads();

    // ---- rescue (rare): exact fp32 rescan (validated R4 arithmetic) ----
    for (int row = w; row < CROWS; row += 4) {
        if (sBest[row] >= 0) continue;            // wave-uniform
        int swz = row & 7;
        float bs = -1e30f; int bk = 0;
        #pragma unroll 1
        for (int j = 0; j < 4; ++j) {
            int k = j * 64 + lane;
            float s = -0.5f * c2ws[m * 256 + k];
            #pragma unroll
            for (int d4 = 0; d4 < 16; ++d4) {
                f4 cvv = cb4m[k * 16 + d4];
                f4 zz  = sZ4[row * 16 + (d4 ^ swz)];
                s = fmaf(zz.x, cvv.x, s); s = fmaf(zz.y, cvv.y, s);
                s = fmaf(zz.z, cvv.z, s); s = fmaf(zz.w, cvv.w, s);
            }
            if (s > bs) { bs = s; bk = k; }
        }
        #pragma unroll
        for (int off = 1; off < 64; off <<= 1) {
            float ov = __shfl_xor(bs, off, 64);
            int   ok = __shfl_xor(bk, off, 64);
            if (ov > bs || (ov == bs && ok < bk)) { bs = ov; bk = ok; }
        }
        if (lane == 0) sBest[row] = bk;
    }
    __syncthreads();

    // ---- outputs: quantized (exact codebook copy), index, loss partial ----
    float lsum = 0.f;
    {
        int row = tid >> 2, quad = tid & 3;
        int k = sBest[row];
        int b = chunk * 64 + row;
        int swz = row & 7;
        const f4* q4 = cb4m + (size_t)k * 16 + quad * 4;
        f4*       o4 = reinterpret_cast<f4*>(out + ((size_t)b * 64 + m) * 64) + quad * 4;
        #pragma unroll
        for (int e = 0; e < 4; ++e) {
            f4 qv = q4[e];
            f4 zv = sZ4[row * 16 + ((quad * 4 + e) ^ swz)];
            o4[e] = qv;
            float d0 = qv.x - zv.x, d1 = qv.y - zv.y;
            float d2 = qv.z - zv.z, d3 = qv.w - zv.w;
            lsum = fmaf(d0, d0, lsum); lsum = fmaf(d1, d1, lsum);
            lsum = fmaf(d2, d2, lsum); lsum = fmaf(d3, d3, lsum);
        }
    }
    if (tid < CROWS)
        out[IDX_BASE + (size_t)(chunk * 64 + tid) * 64 + m] = (float)sBest[tid];
    #pragma unroll
    for (int off = 1; off < 64; off <<= 1) lsum += __shfl_xor(lsum, off, 64);
    if (lane == 0) sW[w] = lsum;
    __syncthreads();
    if (tid == 0) partial[bx] = (sW[0] + sW[1]) + (sW[2] + sW[3]);
}

// ---- deterministic final reduction of 4096 block partials -> q_loss ----
__global__ __launch_bounds__(256) void pq_loss(const float* __restrict__ partial,
                                               float* __restrict__ out)
{
    __shared__ float sW[4];
    float s = 0.f;
    #pragma unroll
    for (int i = 0; i < 16; ++i) s += partial[threadIdx.x + i * 256];
    #pragma unroll
    for (int off = 1; off < 64; off <<= 1) s += __shfl_xor(s, off, 64);
    if ((threadIdx.x & 63) == 0) sW[threadIdx.x >> 6] = s;
    __syncthreads();
    if (threadIdx.x == 0)
        out[LOSS_IDX] = ((sW[0] + sW[1]) + (sW[2] + sW[3])) * (1.25f / 16777216.0f);
}

extern "C" void kernel_launch(void* const* d_in, const int* in_sizes, int n_in,
                              void* d_out, int out_size, void* d_ws, size_t ws_size,
                              hipStream_t stream) {
    const float* zp  = (const float*)d_in[0];
    const float* cbp = (const float*)d_in[1];
    float* outp = (float*)d_out;
    float* c2ws = (float*)d_ws;                  // 64*256 floats = 64 KB
    float* part = (float*)d_ws + 64 * 256;       // 4096 floats

    pq_c2  <<<dim3(64),   dim3(256), 0, stream>>>(cbp, c2ws);
    pq_main<<<dim3(4096), dim3(256), 0, stream>>>(zp, cbp, c2ws, outp, part);
    pq_loss<<<dim3(1),    dim3(256), 0, stream>>>(part, outp);
}